// Round 2
// baseline (97.035 us; speedup 1.0000x reference)
//
#include <hip/hip_runtime.h>
#include <hip/hip_bf16.h>
#include <math.h>

// Problem constants
#define N_CELLS 8192
#define D_DIM 64
#define H_DIM 128
#define GRID_SZ 256
#define NBINS (GRID_SZ * GRID_SZ)
#define BUCKET_CAP 16

// ---------------- K1: fill spatial-hash buckets ----------------
__global__ __launch_bounds__(256) void bin_fill(const int* __restrict__ positions,
                                                int* __restrict__ counts,
                                                int* __restrict__ buckets) {
    int i = blockIdx.x * 256 + threadIdx.x;
    if (i >= N_CELLS) return;
    int p0 = positions[2 * i], p1 = positions[2 * i + 1];
    int bin = p0 * GRID_SZ + p1;
    int slot = atomicAdd(&counts[bin], 1);
    if (slot < BUCKET_CAP) buckets[bin * BUCKET_CAP + slot] = i;
}

// ---------------- K2: neighbor mean + assemble xh = [states | nbr_mean | h] ----------------
__global__ __launch_bounds__(256) void build_xh(const int* __restrict__ positions,
                                                const float* __restrict__ states,
                                                const float* __restrict__ h,
                                                const int* __restrict__ counts,
                                                const int* __restrict__ buckets,
                                                float* __restrict__ xh) {
    int wave = threadIdx.x >> 6;
    int lane = threadIdx.x & 63;
    int i = blockIdx.x * 4 + wave;   // one wave per cell
    int p0 = positions[2 * i], p1 = positions[2 * i + 1];

    float acc = 0.0f;
    int cnt = 0;
    #pragma unroll
    for (int da = -3; da <= 3; ++da) {
        int q0 = p0 + da;
        if (q0 < 0 || q0 >= GRID_SZ) continue;
        int maxdb2 = 9 - da * da;
        #pragma unroll
        for (int db = -3; db <= 3; ++db) {
            if (db * db > maxdb2) continue;
            int q1 = p1 + db;
            if (q1 < 0 || q1 >= GRID_SZ) continue;
            int bin = q0 * GRID_SZ + q1;
            int c = counts[bin];
            if (c > BUCKET_CAP) c = BUCKET_CAP;
            for (int s = 0; s < c; ++s) {
                int j = buckets[bin * BUCKET_CAP + s];
                if (j == i) continue;   // exclude self (same-position others DO count)
                cnt++;
                acc += states[j * D_DIM + lane];
            }
        }
    }
    float nbr = (cnt > 0) ? acc / (float)cnt : 0.0f;

    float* row = xh + (size_t)i * 256;
    row[lane]        = states[i * D_DIM + lane];
    row[64 + lane]   = nbr;
    row[128 + lane]  = h[i * H_DIM + lane];
    row[192 + lane]  = h[i * H_DIM + 64 + lane];
}

// ---------------- K3: gates = xh @ [W_ih | W_hh]^T + b  ([8192,256] x [256,512]) ----------------
__global__ __launch_bounds__(256) void gemm_gates(const float* __restrict__ xh,
                                                  const float* __restrict__ Wih,
                                                  const float* __restrict__ Whh,
                                                  const float* __restrict__ bias,
                                                  float* __restrict__ gates) {
    __shared__ float As[64][68];  // As[k][n], row stride 68 floats = 272B (16B-aligned)
    __shared__ float Bs[64][68];  // Bs[k][g]

    int tid = threadIdx.x;
    int nb = blockIdx.x & 127;   // 128 row blocks
    int gb = blockIdx.x >> 7;    // 8 col blocks
    int n0 = nb * 64, g0 = gb * 64;
    int tg = tid & 15, tn = tid >> 4;   // 16x16 threads, 4x4 outputs each

    float acc[4][4] = {};

    for (int kt = 0; kt < 4; ++kt) {
        int k0 = kt * 64;
        const float* W = (k0 < 128) ? Wih : Whh;   // both are [512,128] row-major
        int ks = k0 & 127;
        #pragma unroll
        for (int e = 0; e < 16; ++e) {
            int idx = e * 256 + tid;
            int kk = idx & 63, rr = idx >> 6;
            As[kk][rr] = xh[(size_t)(n0 + rr) * 256 + k0 + kk];
            Bs[kk][rr] = W[(g0 + rr) * 128 + ks + kk];
        }
        __syncthreads();
        #pragma unroll 8
        for (int kk = 0; kk < 64; ++kk) {
            const float4 av = *reinterpret_cast<const float4*>(&As[kk][tn * 4]);
            const float4 bv = *reinterpret_cast<const float4*>(&Bs[kk][tg * 4]);
            const float a[4] = {av.x, av.y, av.z, av.w};
            const float b4[4] = {bv.x, bv.y, bv.z, bv.w};
            #pragma unroll
            for (int i2 = 0; i2 < 4; ++i2)
                #pragma unroll
                for (int j2 = 0; j2 < 4; ++j2)
                    acc[i2][j2] = fmaf(a[i2], b4[j2], acc[i2][j2]);
        }
        __syncthreads();
    }

    float bj[4];
    #pragma unroll
    for (int j2 = 0; j2 < 4; ++j2) bj[j2] = bias[g0 + tg * 4 + j2];
    #pragma unroll
    for (int i2 = 0; i2 < 4; ++i2) {
        float4 o;
        o.x = acc[i2][0] + bj[0];
        o.y = acc[i2][1] + bj[1];
        o.z = acc[i2][2] + bj[2];
        o.w = acc[i2][3] + bj[3];
        *reinterpret_cast<float4*>(&gates[(size_t)(n0 + tn * 4 + i2) * 512 + g0 + tg * 4]) = o;
    }
}

// ---------------- K4: LSTM pointwise ----------------
__global__ __launch_bounds__(256) void lstm_point(const float* __restrict__ gates,
                                                  const float* __restrict__ c,
                                                  float* __restrict__ h_new) {
    int idx = blockIdx.x * 256 + threadIdx.x;   // N*H = 1M
    int n = idx >> 7, hh = idx & 127;
    const float* gr = gates + (size_t)n * 512;
    float ig = gr[hh], fg = gr[128 + hh], gg = gr[256 + hh], og = gr[384 + hh];
    float cv = c[idx];
    float si = 1.0f / (1.0f + expf(-ig));
    float sf = 1.0f / (1.0f + expf(-fg));
    float so = 1.0f / (1.0f + expf(-og));
    float cn = sf * cv + si * tanhf(gg);
    h_new[idx] = so * tanhf(cn);
}

// ---------------- K5: output heads ----------------
__global__ __launch_bounds__(256) void out_heads(const float* __restrict__ h_new,
                                                 const float* __restrict__ W_out,
                                                 const float* __restrict__ W_role,
                                                 float* __restrict__ out) {
    __shared__ float Ws[128][64];   // 32 KB
    __shared__ float Wr[128][4];
    int tid = threadIdx.x;
    for (int e = tid; e < 128 * 64; e += 256) Ws[e >> 6][e & 63] = W_out[e];
    for (int e = tid; e < 128 * 3; e += 256) Wr[e / 3][e % 3] = W_role[e];
    __syncthreads();

    int n = blockIdx.x * 4 + (tid >> 6);   // one wave per cell
    int lane = tid & 63;
    float acc = 0.0f, r0 = 0.0f, r1 = 0.0f, r2 = 0.0f;
    const float* hr = h_new + (size_t)n * H_DIM;
    #pragma unroll 4
    for (int k = 0; k < H_DIM; ++k) {
        float hk = hr[k];
        acc = fmaf(hk, Ws[k][lane], acc);
        r0 = fmaf(hk, Wr[k][0], r0);
        r1 = fmaf(hk, Wr[k][1], r1);
        r2 = fmaf(hk, Wr[k][2], r2);
    }
    out[(size_t)n * D_DIM + lane] = acc;

    float m = fmaxf(r0, fmaxf(r1, r2));
    float e0 = expf(r0 - m), e1 = expf(r1 - m), e2 = expf(r2 - m);
    float s = e0 + e1 + e2;
    if (lane < 3) {
        float p = (lane == 0) ? e0 : ((lane == 1) ? e1 : e2);
        out[(size_t)N_CELLS * D_DIM + (size_t)n * 3 + lane] = p / s;
    }
}

// ---------------- host launcher ----------------
extern "C" void kernel_launch(void* const* d_in, const int* in_sizes, int n_in,
                              void* d_out, int out_size, void* d_ws, size_t ws_size,
                              hipStream_t stream) {
    const int*   positions = (const int*)d_in[0];
    const float* states    = (const float*)d_in[1];
    const float* h         = (const float*)d_in[2];
    const float* c         = (const float*)d_in[3];
    const float* Wih       = (const float*)d_in[4];
    const float* Whh       = (const float*)d_in[5];
    const float* bias      = (const float*)d_in[6];
    const float* Wout      = (const float*)d_in[7];
    const float* Wrole     = (const float*)d_in[8];
    float* out             = (float*)d_out;

    char* ws = (char*)d_ws;
    int*   counts  = (int*)ws;                              // 256 KB
    int*   buckets = (int*)(ws + 262144);                   // 4 MB
    float* xh      = (float*)(ws + 4456448);                // 8 MB   [N,256]
    float* gates   = (float*)(ws + 12845056);               // 16 MB  [N,512]
    float* h_new   = (float*)(ws + 29622272);               // 4 MB   [N,128]

    hipMemsetAsync(counts, 0, NBINS * sizeof(int), stream);
    bin_fill<<<N_CELLS / 256, 256, 0, stream>>>(positions, counts, buckets);
    build_xh<<<N_CELLS / 4, 256, 0, stream>>>(positions, states, h, counts, buckets, xh);
    gemm_gates<<<128 * 8, 256, 0, stream>>>(xh, Wih, Whh, bias, gates);
    lstm_point<<<(N_CELLS * H_DIM) / 256, 256, 0, stream>>>(gates, c, h_new);
    out_heads<<<N_CELLS / 4, 256, 0, stream>>>(h_new, Wout, Wrole, out);
}

// Round 3
// 69.680 us; speedup vs baseline: 1.3926x; 1.3926x over previous
//
#include <hip/hip_runtime.h>
#include <hip/hip_bf16.h>
#include <math.h>

#define N_CELLS 8192
#define D_DIM 64
#define H_DIM 128
#define GRID_SZ 256
#define NBINS (GRID_SZ * GRID_SZ)
#define BUCKET_CAP 16

typedef short bf16x8 __attribute__((ext_vector_type(8)));
typedef float f32x4 __attribute__((ext_vector_type(4)));

// ---------------- K1: fill spatial-hash buckets ----------------
__global__ __launch_bounds__(256) void bin_fill(const int* __restrict__ positions,
                                                int* __restrict__ counts,
                                                int* __restrict__ buckets) {
    int i = blockIdx.x * 256 + threadIdx.x;
    if (i >= N_CELLS) return;
    int p0 = positions[2 * i], p1 = positions[2 * i + 1];
    int bin = p0 * GRID_SZ + p1;
    int slot = atomicAdd(&counts[bin], 1);
    if (slot < BUCKET_CAP) buckets[bin * BUCKET_CAP + slot] = i;
}

// ---------------- K2: neighbor mean + assemble xh(bf16) = [states | nbr_mean | h] ----------------
__global__ __launch_bounds__(256) void build_xh(const int* __restrict__ positions,
                                                const float* __restrict__ states,
                                                const float* __restrict__ h,
                                                const int* __restrict__ counts,
                                                const int* __restrict__ buckets,
                                                __hip_bfloat16* __restrict__ xh) {
    int wave = threadIdx.x >> 6;
    int lane = threadIdx.x & 63;
    int i = blockIdx.x * 4 + wave;   // one wave per cell
    int p0 = positions[2 * i], p1 = positions[2 * i + 1];

    float acc = 0.0f;
    int cnt = 0;
    #pragma unroll
    for (int da = -3; da <= 3; ++da) {
        int q0 = p0 + da;
        if (q0 < 0 || q0 >= GRID_SZ) continue;
        int maxdb2 = 9 - da * da;
        #pragma unroll
        for (int db = -3; db <= 3; ++db) {
            if (db * db > maxdb2) continue;
            int q1 = p1 + db;
            if (q1 < 0 || q1 >= GRID_SZ) continue;
            int bin = q0 * GRID_SZ + q1;
            int c = counts[bin];
            if (c > BUCKET_CAP) c = BUCKET_CAP;
            for (int s = 0; s < c; ++s) {
                int j = buckets[bin * BUCKET_CAP + s];
                if (j == i) continue;   // exclude self (same-position others DO count)
                cnt++;
                acc += states[j * D_DIM + lane];
            }
        }
    }
    float nbr = (cnt > 0) ? acc / (float)cnt : 0.0f;

    __hip_bfloat16* row = xh + (size_t)i * 256;
    row[lane]       = __float2bfloat16(states[i * D_DIM + lane]);
    row[64 + lane]  = __float2bfloat16(nbr);
    row[128 + lane] = __float2bfloat16(h[i * H_DIM + lane]);
    row[192 + lane] = __float2bfloat16(h[i * H_DIM + 64 + lane]);
}

// ---------------- K3: pack weights to bf16 with gate-interleaved row permutation ----------------
// Wb row g' (0..511): group = g'>>6 (16 h per group), c6 = g'&63, gate = c6>>4, hl = c6&15.
// original gate row = gate*128 + group*16 + hl.  Wb[g'][0:128] = W_ih[orig], [128:256] = W_hh[orig].
__global__ __launch_bounds__(256) void wcvt(const float* __restrict__ Wih,
                                            const float* __restrict__ Whh,
                                            __hip_bfloat16* __restrict__ Wb) {
    int idx = blockIdx.x * 256 + threadIdx.x;   // 512*256 = 131072
    int gp = idx >> 8, k = idx & 255;
    int group = gp >> 6, c6 = gp & 63, gate = c6 >> 4, hl = c6 & 15;
    int orig = gate * 128 + group * 16 + hl;
    float v = (k < 128) ? Wih[orig * 128 + k] : Whh[orig * 128 + (k - 128)];
    Wb[idx] = __float2bfloat16(v);
}

// ---------------- K4: fused MFMA gate-GEMM + LSTM pointwise ----------------
// C[8192,512] = xh[8192,256] @ Wb[512,256]^T, 128x128 tiles, 4 waves (2x2), 16x16x32 bf16 MFMA.
// LDS tiles XOR-swizzled (T2): byte ^= (row&7)<<4; source pre-swizzled for global_load_lds (rule #21).
__global__ __launch_bounds__(256) void gemm_lstm(const __hip_bfloat16* __restrict__ xh,
                                                 const __hip_bfloat16* __restrict__ Wb,
                                                 const float* __restrict__ bias,
                                                 const float* __restrict__ c_in,
                                                 float* __restrict__ h_new) {
    __shared__ char smem[65536];
    char* As = smem;            // 128 rows x 256B (BK=128 bf16)
    char* Bs = smem + 32768;

    const int tid  = threadIdx.x;
    const int lane = tid & 63;
    const int wid  = tid >> 6;
    const int wrow = wid >> 1, wcol = wid & 1;
    const int nb = blockIdx.x >> 2, gb = blockIdx.x & 3;
    const int n0 = nb * 128, g0 = gb * 128;

    const char* aG = (const char*)xh;   // row stride 512B
    const char* bG = (const char*)Wb;   // row stride 512B

    const int rr = tid >> 4;            // staging: row-in-round
    const int cs = (tid & 15) << 4;     // staging: 16B slot (linear LDS dest)

    f32x4 acc[4][4] = {};               // [mi][ni]

    for (int kc = 0; kc < 2; ++kc) {
        if (kc) __syncthreads();        // protect LDS reuse
        #pragma unroll
        for (int e = 0; e < 8; ++e) {
            int row = e * 16 + rr;
            int sc = cs ^ ((row & 7) << 4);   // pre-swizzled source
            __builtin_amdgcn_global_load_lds(
                (const __attribute__((address_space(1))) void*)(aG + (size_t)(n0 + row) * 512 + kc * 256 + sc),
                (__attribute__((address_space(3))) void*)(As + row * 256 + cs), 16, 0, 0);
        }
        #pragma unroll
        for (int e = 0; e < 8; ++e) {
            int row = e * 16 + rr;
            int sc = cs ^ ((row & 7) << 4);
            __builtin_amdgcn_global_load_lds(
                (const __attribute__((address_space(1))) void*)(bG + (size_t)(g0 + row) * 512 + kc * 256 + sc),
                (__attribute__((address_space(3))) void*)(Bs + row * 256 + cs), 16, 0, 0);
        }
        __syncthreads();

        #pragma unroll
        for (int ks = 0; ks < 4; ++ks) {
            bf16x8 av[4], bv[4];
            #pragma unroll
            for (int mi = 0; mi < 4; ++mi) {
                int arow = wrow * 64 + mi * 16 + (lane & 15);
                int acol = (ks * 64 + ((lane >> 4) << 4)) ^ ((arow & 7) << 4);  // swizzled read
                av[mi] = *(const bf16x8*)(As + arow * 256 + acol);
            }
            #pragma unroll
            for (int ni = 0; ni < 4; ++ni) {
                int brow = wcol * 64 + ni * 16 + (lane & 15);
                int bcol = (ks * 64 + ((lane >> 4) << 4)) ^ ((brow & 7) << 4);
                bv[ni] = *(const bf16x8*)(Bs + brow * 256 + bcol);
            }
            #pragma unroll
            for (int mi = 0; mi < 4; ++mi)
                #pragma unroll
                for (int ni = 0; ni < 4; ++ni)
                    acc[mi][ni] = __builtin_amdgcn_mfma_f32_16x16x32_bf16(av[mi], bv[ni], acc[mi][ni], 0, 0, 0);
        }
    }

    // ---- fused LSTM pointwise epilogue (i/f/g/o are in-lane across ni=0..3) ----
    const int group = gb * 2 + wcol;
    const int h = group * 16 + (lane & 15);
    const float bi = bias[h], bff = bias[128 + h], bgg = bias[256 + h], boo = bias[384 + h];
    #pragma unroll
    for (int mi = 0; mi < 4; ++mi) {
        #pragma unroll
        for (int r = 0; r < 4; ++r) {
            int m = n0 + wrow * 64 + mi * 16 + ((lane >> 4) << 2) + r;
            float ig = acc[mi][0][r] + bi;
            float fg = acc[mi][1][r] + bff;
            float gg = acc[mi][2][r] + bgg;
            float og = acc[mi][3][r] + boo;
            float cv = c_in[m * H_DIM + h];
            float si = 1.0f / (1.0f + expf(-ig));
            float sf = 1.0f / (1.0f + expf(-fg));
            float so = 1.0f / (1.0f + expf(-og));
            float cn = sf * cv + si * tanhf(gg);
            h_new[m * H_DIM + h] = so * tanhf(cn);
        }
    }
}

// ---------------- K5: output heads ----------------
__global__ __launch_bounds__(256) void out_heads(const float* __restrict__ h_new,
                                                 const float* __restrict__ W_out,
                                                 const float* __restrict__ W_role,
                                                 float* __restrict__ out) {
    __shared__ float Ws[128][64];   // 32 KB
    __shared__ float Wr[128][4];
    int tid = threadIdx.x;
    for (int e = tid; e < 128 * 64; e += 256) Ws[e >> 6][e & 63] = W_out[e];
    for (int e = tid; e < 128 * 3; e += 256) Wr[e / 3][e % 3] = W_role[e];
    __syncthreads();

    int n = blockIdx.x * 4 + (tid >> 6);   // one wave per cell
    int lane = tid & 63;
    float acc = 0.0f, r0 = 0.0f, r1 = 0.0f, r2 = 0.0f;
    const float* hr = h_new + (size_t)n * H_DIM;
    #pragma unroll 4
    for (int k = 0; k < H_DIM; ++k) {
        float hk = hr[k];
        acc = fmaf(hk, Ws[k][lane], acc);
        r0 = fmaf(hk, Wr[k][0], r0);
        r1 = fmaf(hk, Wr[k][1], r1);
        r2 = fmaf(hk, Wr[k][2], r2);
    }
    out[(size_t)n * D_DIM + lane] = acc;

    float m = fmaxf(r0, fmaxf(r1, r2));
    float e0 = expf(r0 - m), e1 = expf(r1 - m), e2 = expf(r2 - m);
    float s = e0 + e1 + e2;
    if (lane < 3) {
        float p = (lane == 0) ? e0 : ((lane == 1) ? e1 : e2);
        out[(size_t)N_CELLS * D_DIM + (size_t)n * 3 + lane] = p / s;
    }
}

// ---------------- host launcher ----------------
extern "C" void kernel_launch(void* const* d_in, const int* in_sizes, int n_in,
                              void* d_out, int out_size, void* d_ws, size_t ws_size,
                              hipStream_t stream) {
    const int*   positions = (const int*)d_in[0];
    const float* states    = (const float*)d_in[1];
    const float* h         = (const float*)d_in[2];
    const float* c         = (const float*)d_in[3];
    const float* Wih       = (const float*)d_in[4];
    const float* Whh       = (const float*)d_in[5];
    const float* bias      = (const float*)d_in[6];
    const float* Wout      = (const float*)d_in[7];
    const float* Wrole     = (const float*)d_in[8];
    float* out             = (float*)d_out;

    char* ws = (char*)d_ws;
    int*            counts  = (int*)ws;                         // 256 KB @ 0
    int*            buckets = (int*)(ws + 262144);              // 4 MB
    __hip_bfloat16* xh      = (__hip_bfloat16*)(ws + 4456448);  // 4 MB   [N,256] bf16
    __hip_bfloat16* Wb      = (__hip_bfloat16*)(ws + 8650752);  // 256 KB [512,256] bf16
    float*          h_new   = (float*)(ws + 8912896);           // 4 MB   [N,128] f32

    hipMemsetAsync(counts, 0, NBINS * sizeof(int), stream);
    bin_fill<<<N_CELLS / 256, 256, 0, stream>>>(positions, counts, buckets);
    build_xh<<<N_CELLS / 4, 256, 0, stream>>>(positions, states, h, counts, buckets, xh);
    wcvt<<<512, 256, 0, stream>>>(Wih, Whh, Wb);
    gemm_lstm<<<256, 256, 0, stream>>>(xh, Wb, bias, c, h_new);
    out_heads<<<N_CELLS / 4, 256, 0, stream>>>(h_new, Wout, Wrole, out);
}

// Round 4
// 69.520 us; speedup vs baseline: 1.3958x; 1.0023x over previous
//
#include <hip/hip_runtime.h>
#include <hip/hip_bf16.h>
#include <math.h>

#define N_CELLS 8192
#define D_DIM 64
#define H_DIM 128
#define GRID_SZ 256
#define NBINS (GRID_SZ * GRID_SZ)
#define BUCKET_CAP 16

typedef short bf16x8 __attribute__((ext_vector_type(8)));
typedef float f32x4 __attribute__((ext_vector_type(4)));

// ---------------- K0: clear bin counts (replaces 39us rocclr fillBuffer) ----------------
__global__ __launch_bounds__(256) void clear_counts(int4* __restrict__ counts4) {
    counts4[blockIdx.x * 256 + threadIdx.x] = make_int4(0, 0, 0, 0);
}

// ---------------- K1: fill spatial-hash buckets ----------------
__global__ __launch_bounds__(256) void bin_fill(const int* __restrict__ positions,
                                                int* __restrict__ counts,
                                                int* __restrict__ buckets) {
    int i = blockIdx.x * 256 + threadIdx.x;
    if (i >= N_CELLS) return;
    int p0 = positions[2 * i], p1 = positions[2 * i + 1];
    int bin = p0 * GRID_SZ + p1;
    int slot = atomicAdd(&counts[bin], 1);
    if (slot < BUCKET_CAP) buckets[bin * BUCKET_CAP + slot] = i;
}

// ---------------- K2: neighbor mean + assemble xh(bf16) = [states | nbr_mean | h] ----------------
__global__ __launch_bounds__(256) void build_xh(const int* __restrict__ positions,
                                                const float* __restrict__ states,
                                                const float* __restrict__ h,
                                                const int* __restrict__ counts,
                                                const int* __restrict__ buckets,
                                                __hip_bfloat16* __restrict__ xh) {
    int wave = threadIdx.x >> 6;
    int lane = threadIdx.x & 63;
    int i = blockIdx.x * 4 + wave;   // one wave per cell
    int p0 = positions[2 * i], p1 = positions[2 * i + 1];

    float acc = 0.0f;
    int cnt = 0;
    #pragma unroll
    for (int da = -3; da <= 3; ++da) {
        int q0 = p0 + da;
        if (q0 < 0 || q0 >= GRID_SZ) continue;
        int maxdb2 = 9 - da * da;
        #pragma unroll
        for (int db = -3; db <= 3; ++db) {
            if (db * db > maxdb2) continue;
            int q1 = p1 + db;
            if (q1 < 0 || q1 >= GRID_SZ) continue;
            int bin = q0 * GRID_SZ + q1;
            int c = counts[bin];
            if (c > BUCKET_CAP) c = BUCKET_CAP;
            for (int s = 0; s < c; ++s) {
                int j = buckets[bin * BUCKET_CAP + s];
                if (j == i) continue;   // exclude self (same-position others DO count)
                cnt++;
                acc += states[j * D_DIM + lane];
            }
        }
    }
    float nbr = (cnt > 0) ? acc / (float)cnt : 0.0f;

    __hip_bfloat16* row = xh + (size_t)i * 256;
    row[lane]       = __float2bfloat16(states[i * D_DIM + lane]);
    row[64 + lane]  = __float2bfloat16(nbr);
    row[128 + lane] = __float2bfloat16(h[i * H_DIM + lane]);
    row[192 + lane] = __float2bfloat16(h[i * H_DIM + 64 + lane]);
}

// ---------------- K3: pack weights to bf16 with gate-interleaved row permutation ----------------
// Wb row g' (0..511): group = g'>>6 (16 h per group), c6 = g'&63, gate = c6>>4, hl = c6&15.
// original gate row = gate*128 + group*16 + hl.  Wb[g'][0:128] = W_ih[orig], [128:256] = W_hh[orig].
__global__ __launch_bounds__(256) void wcvt(const float* __restrict__ Wih,
                                            const float* __restrict__ Whh,
                                            __hip_bfloat16* __restrict__ Wb) {
    int idx = blockIdx.x * 256 + threadIdx.x;   // 512*256 = 131072
    int gp = idx >> 8, k = idx & 255;
    int group = gp >> 6, c6 = gp & 63, gate = c6 >> 4, hl = c6 & 15;
    int orig = gate * 128 + group * 16 + hl;
    float v = (k < 128) ? Wih[orig * 128 + k] : Whh[orig * 128 + (k - 128)];
    Wb[idx] = __float2bfloat16(v);
}

// ---------------- K4: fused MFMA gate-GEMM + LSTM pointwise ----------------
// C[8192,512] = xh[8192,256] @ Wb[512,256]^T, 128x128 tiles, 4 waves (2x2), 16x16x32 bf16 MFMA.
// LDS tiles XOR-swizzled (T2): byte ^= (row&7)<<4; source pre-swizzled for global_load_lds (rule #21).
__global__ __launch_bounds__(256) void gemm_lstm(const __hip_bfloat16* __restrict__ xh,
                                                 const __hip_bfloat16* __restrict__ Wb,
                                                 const float* __restrict__ bias,
                                                 const float* __restrict__ c_in,
                                                 float* __restrict__ h_new) {
    __shared__ char smem[65536];
    char* As = smem;            // 128 rows x 256B (BK=128 bf16)
    char* Bs = smem + 32768;

    const int tid  = threadIdx.x;
    const int lane = tid & 63;
    const int wid  = tid >> 6;
    const int wrow = wid >> 1, wcol = wid & 1;
    const int nb = blockIdx.x >> 2, gb = blockIdx.x & 3;
    const int n0 = nb * 128, g0 = gb * 128;

    const char* aG = (const char*)xh;   // row stride 512B
    const char* bG = (const char*)Wb;   // row stride 512B

    const int rr = tid >> 4;            // staging: row-in-round
    const int cs = (tid & 15) << 4;     // staging: 16B slot (linear LDS dest)

    f32x4 acc[4][4] = {};               // [mi][ni]

    for (int kc = 0; kc < 2; ++kc) {
        if (kc) __syncthreads();        // protect LDS reuse
        #pragma unroll
        for (int e = 0; e < 8; ++e) {
            int row = e * 16 + rr;
            int sc = cs ^ ((row & 7) << 4);   // pre-swizzled source
            __builtin_amdgcn_global_load_lds(
                (const __attribute__((address_space(1))) void*)(aG + (size_t)(n0 + row) * 512 + kc * 256 + sc),
                (__attribute__((address_space(3))) void*)(As + row * 256 + cs), 16, 0, 0);
        }
        #pragma unroll
        for (int e = 0; e < 8; ++e) {
            int row = e * 16 + rr;
            int sc = cs ^ ((row & 7) << 4);
            __builtin_amdgcn_global_load_lds(
                (const __attribute__((address_space(1))) void*)(bG + (size_t)(g0 + row) * 512 + kc * 256 + sc),
                (__attribute__((address_space(3))) void*)(Bs + row * 256 + cs), 16, 0, 0);
        }
        __syncthreads();

        #pragma unroll
        for (int ks = 0; ks < 4; ++ks) {
            bf16x8 av[4], bv[4];
            #pragma unroll
            for (int mi = 0; mi < 4; ++mi) {
                int arow = wrow * 64 + mi * 16 + (lane & 15);
                int acol = (ks * 64 + ((lane >> 4) << 4)) ^ ((arow & 7) << 4);  // swizzled read
                av[mi] = *(const bf16x8*)(As + arow * 256 + acol);
            }
            #pragma unroll
            for (int ni = 0; ni < 4; ++ni) {
                int brow = wcol * 64 + ni * 16 + (lane & 15);
                int bcol = (ks * 64 + ((lane >> 4) << 4)) ^ ((brow & 7) << 4);
                bv[ni] = *(const bf16x8*)(Bs + brow * 256 + bcol);
            }
            #pragma unroll
            for (int mi = 0; mi < 4; ++mi)
                #pragma unroll
                for (int ni = 0; ni < 4; ++ni)
                    acc[mi][ni] = __builtin_amdgcn_mfma_f32_16x16x32_bf16(av[mi], bv[ni], acc[mi][ni], 0, 0, 0);
        }
    }

    // ---- fused LSTM pointwise epilogue (i/f/g/o are in-lane across ni=0..3) ----
    const int group = gb * 2 + wcol;
    const int h = group * 16 + (lane & 15);
    const float bi = bias[h], bff = bias[128 + h], bgg = bias[256 + h], boo = bias[384 + h];
    #pragma unroll
    for (int mi = 0; mi < 4; ++mi) {
        #pragma unroll
        for (int r = 0; r < 4; ++r) {
            int m = n0 + wrow * 64 + mi * 16 + ((lane >> 4) << 2) + r;
            float ig = acc[mi][0][r] + bi;
            float fg = acc[mi][1][r] + bff;
            float gg = acc[mi][2][r] + bgg;
            float og = acc[mi][3][r] + boo;
            float cv = c_in[m * H_DIM + h];
            float si = 1.0f / (1.0f + expf(-ig));
            float sf = 1.0f / (1.0f + expf(-fg));
            float so = 1.0f / (1.0f + expf(-og));
            float cn = sf * cv + si * tanhf(gg);
            h_new[m * H_DIM + h] = so * tanhf(cn);
        }
    }
}

// ---------------- K5: output heads ----------------
__global__ __launch_bounds__(256) void out_heads(const float* __restrict__ h_new,
                                                 const float* __restrict__ W_out,
                                                 const float* __restrict__ W_role,
                                                 float* __restrict__ out) {
    __shared__ float Ws[128][64];   // 32 KB
    __shared__ float Wr[128][4];
    int tid = threadIdx.x;
    for (int e = tid; e < 128 * 64; e += 256) Ws[e >> 6][e & 63] = W_out[e];
    for (int e = tid; e < 128 * 3; e += 256) Wr[e / 3][e % 3] = W_role[e];
    __syncthreads();

    int n = blockIdx.x * 4 + (tid >> 6);   // one wave per cell
    int lane = tid & 63;
    float acc = 0.0f, r0 = 0.0f, r1 = 0.0f, r2 = 0.0f;
    const float* hr = h_new + (size_t)n * H_DIM;
    #pragma unroll 4
    for (int k = 0; k < H_DIM; ++k) {
        float hk = hr[k];
        acc = fmaf(hk, Ws[k][lane], acc);
        r0 = fmaf(hk, Wr[k][0], r0);
        r1 = fmaf(hk, Wr[k][1], r1);
        r2 = fmaf(hk, Wr[k][2], r2);
    }
    out[(size_t)n * D_DIM + lane] = acc;

    float m = fmaxf(r0, fmaxf(r1, r2));
    float e0 = expf(r0 - m), e1 = expf(r1 - m), e2 = expf(r2 - m);
    float s = e0 + e1 + e2;
    if (lane < 3) {
        float p = (lane == 0) ? e0 : ((lane == 1) ? e1 : e2);
        out[(size_t)N_CELLS * D_DIM + (size_t)n * 3 + lane] = p / s;
    }
}

// ---------------- host launcher ----------------
extern "C" void kernel_launch(void* const* d_in, const int* in_sizes, int n_in,
                              void* d_out, int out_size, void* d_ws, size_t ws_size,
                              hipStream_t stream) {
    const int*   positions = (const int*)d_in[0];
    const float* states    = (const float*)d_in[1];
    const float* h         = (const float*)d_in[2];
    const float* c         = (const float*)d_in[3];
    const float* Wih       = (const float*)d_in[4];
    const float* Whh       = (const float*)d_in[5];
    const float* bias      = (const float*)d_in[6];
    const float* Wout      = (const float*)d_in[7];
    const float* Wrole     = (const float*)d_in[8];
    float* out             = (float*)d_out;

    char* ws = (char*)d_ws;
    int*            counts  = (int*)ws;                         // 256 KB @ 0
    int*            buckets = (int*)(ws + 262144);              // 4 MB
    __hip_bfloat16* xh      = (__hip_bfloat16*)(ws + 4456448);  // 4 MB   [N,256] bf16
    __hip_bfloat16* Wb      = (__hip_bfloat16*)(ws + 8650752);  // 256 KB [512,256] bf16
    float*          h_new   = (float*)(ws + 8912896);           // 4 MB   [N,128] f32

    clear_counts<<<NBINS / 1024, 256, 0, stream>>>((int4*)counts);
    bin_fill<<<N_CELLS / 256, 256, 0, stream>>>(positions, counts, buckets);
    build_xh<<<N_CELLS / 4, 256, 0, stream>>>(positions, states, h, counts, buckets, xh);
    wcvt<<<512, 256, 0, stream>>>(Wih, Whh, Wb);
    gemm_lstm<<<256, 256, 0, stream>>>(xh, Wb, bias, c, h_new);
    out_heads<<<N_CELLS / 4, 256, 0, stream>>>(h_new, Wout, Wrole, out);
}

// Round 6
// 40.921 us; speedup vs baseline: 2.3712x; 1.6989x over previous
//
#include <hip/hip_runtime.h>
#include <hip/hip_bf16.h>
#include <math.h>

#define N_CELLS 8192
#define D_DIM 64
#define H_DIM 128
#define GRID_SZ 256
#define NBINS (GRID_SZ * GRID_SZ)
#define BUCKET_CAP 16

typedef short bf16x8 __attribute__((ext_vector_type(8)));
typedef float f32x4 __attribute__((ext_vector_type(4)));

static __device__ __forceinline__ short f2bf(float x) {
    __hip_bfloat16 b = __float2bfloat16(x);
    return __builtin_bit_cast(short, b);
}

// ---------------- K0: clear bin counts ----------------
__global__ __launch_bounds__(256) void clear_counts(int4* __restrict__ counts4) {
    counts4[blockIdx.x * 256 + threadIdx.x] = make_int4(0, 0, 0, 0);
}

// ---------------- K1: fill spatial-hash buckets ----------------
__global__ __launch_bounds__(256) void bin_fill(const int* __restrict__ positions,
                                                int* __restrict__ counts,
                                                int* __restrict__ buckets) {
    int i = blockIdx.x * 256 + threadIdx.x;
    if (i >= N_CELLS) return;
    int p0 = positions[2 * i], p1 = positions[2 * i + 1];
    int bin = p0 * GRID_SZ + p1;
    int slot = atomicAdd(&counts[bin], 1);
    if (slot < BUCKET_CAP) buckets[bin * BUCKET_CAP + slot] = i;
}

// ---------------- K2: neighbor mean + xh assembly (blocks 0..2047) fused with
//                      weight pack/permute to bf16 (blocks 2048..2175) ----------------
__global__ __launch_bounds__(256) void build_xh_wcvt(const int* __restrict__ positions,
                                                     const float* __restrict__ states,
                                                     const float* __restrict__ h,
                                                     const int* __restrict__ counts,
                                                     const int* __restrict__ buckets,
                                                     const float* __restrict__ Wih,
                                                     const float* __restrict__ Whh,
                                                     __hip_bfloat16* __restrict__ xh,
                                                     __hip_bfloat16* __restrict__ Wb) {
    int tid = threadIdx.x;
    if (blockIdx.x >= 2048) {
        // weight convert: Wb row g' = [group][gate][hl] permutation
        int idx4 = (blockIdx.x - 2048) * 256 + tid;   // 32768 float4 chunks
        int gp = idx4 >> 6, k4 = (idx4 & 63) << 2;
        int group = gp >> 6, c6 = gp & 63, gate = c6 >> 4, hl = c6 & 15;
        int orig = gate * 128 + group * 16 + hl;
        float4 v = (k4 < 128) ? *(const float4*)(Wih + orig * 128 + k4)
                              : *(const float4*)(Whh + orig * 128 + (k4 - 128));
        short4 o = make_short4(f2bf(v.x), f2bf(v.y), f2bf(v.z), f2bf(v.w));
        *(short4*)((short*)Wb + gp * 256 + k4) = o;
        return;
    }
    int wave = tid >> 6;
    int lane = tid & 63;
    int i = blockIdx.x * 4 + wave;   // one wave per cell
    int p0 = positions[2 * i], p1 = positions[2 * i + 1];

    float acc = 0.0f;
    int cnt = 0;
    #pragma unroll
    for (int da = -3; da <= 3; ++da) {
        int q0 = p0 + da;
        if (q0 < 0 || q0 >= GRID_SZ) continue;
        int maxdb2 = 9 - da * da;
        #pragma unroll
        for (int db = -3; db <= 3; ++db) {
            if (db * db > maxdb2) continue;
            int q1 = p1 + db;
            if (q1 < 0 || q1 >= GRID_SZ) continue;
            int bin = q0 * GRID_SZ + q1;
            int c = counts[bin];
            if (c > BUCKET_CAP) c = BUCKET_CAP;
            for (int s = 0; s < c; ++s) {
                int j = buckets[bin * BUCKET_CAP + s];
                if (j == i) continue;   // exclude self (same-position others DO count)
                cnt++;
                acc += states[j * D_DIM + lane];
            }
        }
    }
    float nbr = (cnt > 0) ? acc / (float)cnt : 0.0f;

    __hip_bfloat16* row = xh + (size_t)i * 256;
    row[lane]       = __float2bfloat16(states[i * D_DIM + lane]);
    row[64 + lane]  = __float2bfloat16(nbr);
    row[128 + lane] = __float2bfloat16(h[i * H_DIM + lane]);
    row[192 + lane] = __float2bfloat16(h[i * H_DIM + 64 + lane]);
}

// ---------------- K3: mega — gate GEMM + LSTM + output heads, fully fused ----------------
// Per block: 32 rows x ALL 512 gate cols. 8 waves (wrow 2 x wcol 4), 16x16x32 bf16 MFMA.
// Then LSTM pointwise in-register -> h (bf16) to LDS -> head MFMAs (W_out as hi+lo bf16 pair).
// LDS XOR-swizzle everywhere: byte ^= (row&7)<<4 (T2); gll uses linear dest + pre-swizzled src.
__global__ __launch_bounds__(512) void mega(const __hip_bfloat16* __restrict__ xh,
                                            const __hip_bfloat16* __restrict__ Wb,
                                            const float* __restrict__ bias,
                                            const float* __restrict__ c_in,
                                            const float* __restrict__ W_out,
                                            const float* __restrict__ W_role,
                                            float* __restrict__ out) {
    __shared__ char smem[69632];           // 68 KB
    char* As = smem;                       // GEMM: 32 rows x 128B
    char* Bs = smem + 4096;                // GEMM: 512 rows x 128B
    char* Hl   = smem;                     // epi: 32 x 256B bf16 h-tile
    char* Wohi = smem + 8192;              // epi: 64 x 256B
    char* Wolo = smem + 24576;             // epi: 64 x 256B
    char* Wr   = smem + 40960;             // epi: 16 x 256B (rows 3..15 zero)

    const int tid  = threadIdx.x;
    const int lane = tid & 63;
    const int wid  = tid >> 6;
    const int wrow = wid >> 2, wcol = wid & 3;
    const int n0 = blockIdx.x * 32;

    const char* aG = (const char*)xh;      // row stride 512B
    const char* bG = (const char*)Wb;      // row stride 512B

    f32x4 acc[8] = {};                     // [ni] over 128 cols of this wave

    for (int kc = 0; kc < 4; ++kc) {       // K = 256 in BK=64 chunks
        if (kc) __syncthreads();
        if (tid < 256) {                   // stage As: 256 x 16B (waves 0-3)
            int row = tid >> 3, slot = (tid & 7) << 4;
            __builtin_amdgcn_global_load_lds(
                (const __attribute__((address_space(1))) void*)(aG + (size_t)(n0 + row) * 512 + kc * 128 + (slot ^ ((row & 7) << 4))),
                (__attribute__((address_space(3))) void*)(As + row * 128 + slot), 16, 0, 0);
        }
        #pragma unroll
        for (int e = 0; e < 8; ++e) {      // stage Bs: 4096 x 16B
            int u = e * 512 + tid;
            int row = u >> 3, slot = (u & 7) << 4;
            __builtin_amdgcn_global_load_lds(
                (const __attribute__((address_space(1))) void*)(bG + (size_t)row * 512 + kc * 128 + (slot ^ ((row & 7) << 4))),
                (__attribute__((address_space(3))) void*)(Bs + row * 128 + slot), 16, 0, 0);
        }
        __syncthreads();

        #pragma unroll
        for (int ks = 0; ks < 2; ++ks) {
            int kb = ks * 64 + ((lane >> 4) << 4);
            int arow = wrow * 16 + (lane & 15);
            bf16x8 av = *(const bf16x8*)(As + arow * 128 + (kb ^ ((arow & 7) << 4)));
            #pragma unroll
            for (int ni = 0; ni < 8; ++ni) {
                int brow = wcol * 128 + ni * 16 + (lane & 15);
                bf16x8 bv = *(const bf16x8*)(Bs + brow * 128 + (kb ^ ((brow & 7) << 4)));
                acc[ni] = __builtin_amdgcn_mfma_f32_16x16x32_bf16(av, bv, acc[ni], 0, 0, 0);
            }
        }
    }
    __syncthreads();   // all GEMM LDS reads complete; repurpose LDS

    // ---- stage head weights: W_out split hi+lo bf16 (transposed to [d][h]), W_role [r][h] ----
    #pragma unroll
    for (int e = 0; e < 16; ++e) {
        int u = e * 512 + tid;             // u = h*64 + d over 8192
        int hh = u >> 6, d = u & 63;
        float w = W_out[u];
        float whi = __bfloat162float(__float2bfloat16(w));
        int off = d * 256 + ((hh * 2) ^ ((d & 7) << 4));
        *(short*)(Wohi + off) = f2bf(whi);
        *(short*)(Wolo + off) = f2bf(w - whi);
    }
    #pragma unroll
    for (int e = 0; e < 4; ++e) {
        int u = e * 512 + tid;             // 2048 slots: r(16) x h(128)
        int r = u >> 7, hh = u & 127;
        float w = (r < 3) ? W_role[hh * 3 + r] : 0.0f;
        *(short*)(Wr + r * 256 + ((hh * 2) ^ ((r & 7) << 4))) = f2bf(w);
    }

    // ---- LSTM pointwise in-register; h -> LDS (bf16, swizzled) ----
    #pragma unroll
    for (int b = 0; b < 2; ++b) {
        int hg = (2 * wcol + b) * 16 + (lane & 15);
        float bi = bias[hg], bff = bias[128 + hg], bgg = bias[256 + hg], boo = bias[384 + hg];
        #pragma unroll
        for (int r = 0; r < 4; ++r) {
            int ml = wrow * 16 + ((lane >> 4) << 2) + r;
            float ig = acc[b * 4 + 0][r] + bi;
            float fg = acc[b * 4 + 1][r] + bff;
            float gg = acc[b * 4 + 2][r] + bgg;
            float og = acc[b * 4 + 3][r] + boo;
            float cv = c_in[(size_t)(n0 + ml) * H_DIM + hg];
            float si = 1.0f / (1.0f + expf(-ig));
            float sf = 1.0f / (1.0f + expf(-fg));
            float so = 1.0f / (1.0f + expf(-og));
            float hn = so * tanhf(sf * cv + si * tanhf(gg));
            *(short*)(Hl + ml * 256 + ((hg * 2) ^ ((ml & 7) << 4))) = f2bf(hn);
        }
    }
    __syncthreads();

    // ---- head GEMMs: out = h @ W_out (hi+lo), roleT = Wr @ h^T ----
    const int rb = wid >> 2, db = wid & 3;
    f32x4 oacc = {};
    f32x4 racc = {};
    #pragma unroll
    for (int ks = 0; ks < 4; ++ks) {       // K = 128
        int kb = ks * 64 + ((lane >> 4) << 4);
        int hrow = rb * 16 + (lane & 15);
        bf16x8 hv = *(const bf16x8*)(Hl + hrow * 256 + (kb ^ ((hrow & 7) << 4)));
        int drow = db * 16 + (lane & 15);
        int woff = drow * 256 + (kb ^ ((drow & 7) << 4));
        bf16x8 whi = *(const bf16x8*)(Wohi + woff);
        bf16x8 wlo = *(const bf16x8*)(Wolo + woff);
        oacc = __builtin_amdgcn_mfma_f32_16x16x32_bf16(hv, whi, oacc, 0, 0, 0);
        oacc = __builtin_amdgcn_mfma_f32_16x16x32_bf16(hv, wlo, oacc, 0, 0, 0);
        if (db == 3) {
            int rrow = lane & 15;
            bf16x8 wr = *(const bf16x8*)(Wr + rrow * 256 + (kb ^ ((rrow & 7) << 4)));
            racc = __builtin_amdgcn_mfma_f32_16x16x32_bf16(wr, hv, racc, 0, 0, 0);
        }
    }
    #pragma unroll
    for (int r = 0; r < 4; ++r) {
        int m = n0 + rb * 16 + ((lane >> 4) << 2) + r;
        out[(size_t)m * D_DIM + db * 16 + (lane & 15)] = oacc[r];
    }
    if (db == 3 && lane < 16) {
        int m = n0 + rb * 16 + lane;
        float l0 = racc[0], l1 = racc[1], l2 = racc[2];
        float mx = fmaxf(l0, fmaxf(l1, l2));
        float e0 = expf(l0 - mx), e1 = expf(l1 - mx), e2 = expf(l2 - mx);
        float s = e0 + e1 + e2;
        float* ro = out + (size_t)N_CELLS * D_DIM + (size_t)m * 3;
        ro[0] = e0 / s; ro[1] = e1 / s; ro[2] = e2 / s;
    }
}

// ---------------- host launcher ----------------
extern "C" void kernel_launch(void* const* d_in, const int* in_sizes, int n_in,
                              void* d_out, int out_size, void* d_ws, size_t ws_size,
                              hipStream_t stream) {
    const int*   positions = (const int*)d_in[0];
    const float* states    = (const float*)d_in[1];
    const float* h         = (const float*)d_in[2];
    const float* c         = (const float*)d_in[3];
    const float* Wih       = (const float*)d_in[4];
    const float* Whh       = (const float*)d_in[5];
    const float* bias      = (const float*)d_in[6];
    const float* Wout      = (const float*)d_in[7];
    const float* Wrole     = (const float*)d_in[8];
    float* out             = (float*)d_out;

    char* ws = (char*)d_ws;
    int*            counts  = (int*)ws;                         // 256 KB @ 0
    int*            buckets = (int*)(ws + 262144);              // 4 MB
    __hip_bfloat16* xh      = (__hip_bfloat16*)(ws + 4456448);  // 4 MB   [N,256] bf16
    __hip_bfloat16* Wb      = (__hip_bfloat16*)(ws + 8650752);  // 256 KB [512,256] bf16

    clear_counts<<<NBINS / 1024, 256, 0, stream>>>((int4*)counts);
    bin_fill<<<N_CELLS / 256, 256, 0, stream>>>(positions, counts, buckets);
    build_xh_wcvt<<<2048 + 128, 256, 0, stream>>>(positions, states, h, counts, buckets,
                                                  Wih, Whh, xh, Wb);
    mega<<<N_CELLS / 32, 512, 0, stream>>>(xh, Wb, bias, c, Wout, Wrole, out);
}